// Round 4
// baseline (1406.307 us; speedup 1.0000x reference)
//
#include <hip/hip_runtime.h>

typedef unsigned int u32;

#define H 80
#define W 80
#define DD 20
#define C 32
#define NPOS (H*W)          // 6400
#define NP3 (NPOS*DD)       // 128000
#define SO 9
#define DO_ 5
#define NDISP (DO_*SO*SO)   // 405

// ---------------- K1: cost volume (float32, zero workspace) ------
// thread = (y, di, x, zg); zg covers 4 z. Loops dj.
__global__ __launch_bounds__(256, 2)
void cost_kernel(const float* __restrict__ f1, const float* __restrict__ f2,
                 float* __restrict__ outc){
    int t  = blockIdx.x * 256 + threadIdx.x;   // 288000 exact
    int zg = t % 5;
    int x  = (t / 5) % W;
    int di = (t / (5 * W)) % SO;
    int y  = t / (5 * W * SO);
    int z0 = zg * 4;
    int pos = y * W + x;

    // f1 fragment: a[c][z], 4 z contiguous per c (16B aligned: 80B row, z0*4 in {0,16,..,64})
    float a[C][4];
    {
        const float* p1 = f1 + pos * DD + z0;
        #pragma unroll
        for (int c = 0; c < C; ++c){
            float4 v = *(const float4*)(p1 + c * NP3);
            a[c][0] = v.x; a[c][1] = v.y; a[c][2] = v.z; a[c][3] = v.w;
        }
    }

    int y2 = y + di - 4;
    bool yok = ((unsigned)y2 < (unsigned)H);
    const float sc = 1.0f / 32.0f;

    #pragma unroll 1
    for (int dj = 0; dj < SO; ++dj){
        int x2 = x + dj - 4;
        bool ok = yok && ((unsigned)x2 < (unsigned)W);
        float acc[DO_][4];
        #pragma unroll
        for (int dk = 0; dk < DO_; ++dk)
            #pragma unroll
            for (int z = 0; z < 4; ++z) acc[dk][z] = 0.f;

        if (ok){
            const float* p2 = f2 + (y2 * W + x2) * DD + z0;
            #pragma unroll
            for (int c = 0; c < C; ++c){
                const float* pc = p2 + c * NP3;
                float bz[12];   // zp window z0-4 .. z0+7 (only idx 2..9 used)
                if (zg > 0){
                    float4 v = *(const float4*)(pc - 4);
                    bz[0] = v.x; bz[1] = v.y; bz[2] = v.z; bz[3] = v.w;
                } else { bz[0]=bz[1]=bz[2]=bz[3]=0.f; }   // zp<0: depth zero-pad
                {
                    float4 v = *(const float4*)(pc);
                    bz[4] = v.x; bz[5] = v.y; bz[6] = v.z; bz[7] = v.w;
                }
                if (zg < 4){
                    float4 v = *(const float4*)(pc + 4);
                    bz[8] = v.x; bz[9] = v.y; bz[10] = v.z; bz[11] = v.w;
                } else { bz[8]=bz[9]=bz[10]=bz[11]=0.f; } // zp>=20: depth zero-pad
                // zp = z0 + z + dk - 2  ->  bz index = z + dk + 2 (in [2,9])
                #pragma unroll
                for (int z = 0; z < 4; ++z)
                    #pragma unroll
                    for (int dk = 0; dk < DO_; ++dk)
                        acc[dk][z] = fmaf(a[c][z], bz[z + dk + 2], acc[dk][z]);
            }
        }
        #pragma unroll
        for (int dk = 0; dk < DO_; ++dk){
            int didx = dk * 81 + di * 9 + dj;    // torch cat order: k slow, i, j fast
            float4 wv;
            wv.x = acc[dk][0] * sc;
            wv.y = acc[dk][1] * sc;
            wv.z = acc[dk][2] * sc;
            wv.w = acc[dk][3] * sc;
            *(float4*)(outc + (size_t)didx * NP3 + pos * DD + z0) = wv;
        }
    }
}

// ---------------- K2: cost-volume mask (float32, zero workspace) ----------------
// block = (8x8 pos tile, di). Masks computed on the fly into LDS.
__global__ __launch_bounds__(256)
void maskvol_kernel(const float* __restrict__ a1, const float* __restrict__ a2,
                    float* __restrict__ outm){
    int bi = blockIdx.x;              // 900 = 100 tiles x 9 di
    int di = bi % 9;
    int tile = bi / 9;
    int ty = (tile / 10) * 8;
    int tx = (tile % 10) * 8;
    __shared__ float m1s[64];
    __shared__ float m2s[8][16];
    int tid = threadIdx.x;

    if (tid < 64){
        int yl = tid >> 3, xl = tid & 7;
        const float* p = a1 + ((ty + yl) * W + tx + xl) * DD;
        float s = 0.f;
        #pragma unroll
        for (int q = 0; q < 5; ++q){
            float4 v = *(const float4*)(p + q * 4);
            s += v.x + v.y + v.z + v.w;
        }
        m1s[tid] = fminf(fmaxf(s, 0.f), 1.f);
    } else if (tid < 192){
        int i = tid - 64;             // 0..127 -> m2 tile [8][16]
        int yl = i >> 4, xl = i & 15;
        int y2 = ty + di - 4 + yl;
        int x2 = tx - 4 + xl;
        float m = 0.f;
        if (((unsigned)y2 < (unsigned)H) && ((unsigned)x2 < (unsigned)W)){
            const float* p = a2 + (y2 * W + x2) * DD;
            float s = 0.f;
            #pragma unroll
            for (int q = 0; q < 5; ++q){
                float4 v = *(const float4*)(p + q * 4);
                s += v.x + v.y + v.z + v.w;
            }
            m = fminf(fmaxf(s, 0.f), 1.f);
        }
        m2s[yl][xl] = m;
    }
    __syncthreads();

    const int TOT = 64 * 45 * 5;      // pos-tile x (dj,dk) x z-quads = 14400
    for (int idx = tid; idx < TOT; idx += 256){
        int zq = idx % 5;
        int p  = (idx / 5) % 64;
        int dd = idx / 320;           // 0..44
        int dj = dd % 9, dk = dd / 9;
        int yl = p >> 3, xl = p & 7;
        int y = ty + yl, xg = tx + xl;
        int pos = y * W + xg;
        float m1v = m1s[p];
        int y2 = y + di - 4, x2 = xg + dj - 4;
        bool sok = ((unsigned)y2 < (unsigned)H) && ((unsigned)x2 < (unsigned)W);
        // spatial pad of mask2 is 1.0 -> value m1v; in-range: clip(m1*m2,0,1)
        float mi = sok ? fminf(m1v * m2s[yl][xl + dj], 1.f) : m1v;
        int zlo = 2 - dk;                    // z < zlo  -> depth pad (m2 pad = 1 -> m1v)
        int zhi = 22 - dk;                   // z >= zhi -> depth pad
        int z = zq * 4;
        float4 wv;
        wv.x = (z + 0 >= zlo && z + 0 < zhi) ? mi : m1v;
        wv.y = (z + 1 >= zlo && z + 1 < zhi) ? mi : m1v;
        wv.z = (z + 2 >= zlo && z + 2 < zhi) ? mi : m1v;
        wv.w = (z + 3 >= zlo && z + 3 < zhi) ? mi : m1v;
        *(float4*)(outm + (size_t)(dk * 81 + di * 9 + dj) * NP3 + pos * DD + z) = wv;
    }
}

extern "C" void kernel_launch(void* const* d_in, const int* in_sizes, int n_in,
                              void* d_out, int out_size, void* d_ws, size_t ws_size,
                              hipStream_t stream) {
    const float* f1 = (const float*)d_in[0];   // mpi1_features [32][80][80][20] f32
    const float* a1 = (const float*)d_in[1];   // mpi1_alpha
    const float* f2 = (const float*)d_in[2];   // mpi2_features
    const float* a2 = (const float*)d_in[3];   // mpi2_alpha
    float* outc = (float*)d_out;                   // cost volume [405][6400][20]
    float* outm = outc + (size_t)NDISP * NP3;      // mask volume, same shape
    (void)d_ws; (void)ws_size;

    cost_kernel<<<1125, 256, 0, stream>>>(f1, f2, outc);
    maskvol_kernel<<<900, 256, 0, stream>>>(a1, a2, outm);
}